// Round 13
// baseline (114.155 us; speedup 1.0000x reference)
//
#include <hip/hip_runtime.h>

#define NJ   17
#define FD   128
#define NC   128
#define NNZ  49
#define FPT  16                 // frames per tile (= MFMA M)
#define XROW (NJ*FD)            // 2176 floats per frame
#define TPB  4                  // tiles per block
#define BUFB 40960              // LDS buffer bytes (10-col bf16 slice)
#define WS_WT 65536             // ws offset of wt[128][64] bf16

typedef __attribute__((ext_vector_type(8))) short bf16x8;
typedef __attribute__((ext_vector_type(4))) float f32x4;

__device__ __forceinline__ ushort f2bf(float f) {   // f32 -> bf16 RNE
  unsigned u = __float_as_uint(f);
  u = (u + 0x7fffu + ((u >> 16) & 1u)) >> 16;
  return (ushort)u;
}
__device__ __forceinline__ float bf2f(ushort s) {
  return __uint_as_float(((unsigned)s) << 16);
}
__device__ __forceinline__ unsigned cvtpk(float a, float b) {
  unsigned r;
  asm("v_cvt_pk_bf16_f32 %0, %1, %2" : "=v"(r) : "v"(a), "v"(b));
  return r;
}
__device__ __forceinline__ bf16x8 pack8(float4 a, float4 b) {
  union { unsigned u[4]; bf16x8 v; } r;
  r.u[0] = cvtpk(a.x, a.y); r.u[1] = cvtpk(a.z, a.w);
  r.u[2] = cvtpk(b.x, b.y); r.u[3] = cvtpk(b.z, b.w);
  return r.v;
}
__device__ __forceinline__ void axpy(f32x4& o, float s, f32x4 h) {
  o[0] += s * h[0]; o[1] += s * h[1]; o[2] += s * h[2]; o[3] += s * h[3];
}

// LDS-only barrier: drains ds ops (lgkm), leaves vmem in flight.
#define BARR() do { asm volatile("s_waitcnt lgkmcnt(0)" ::: "memory"); \
                    __builtin_amdgcn_s_barrier(); \
                    __builtin_amdgcn_sched_barrier(0); } while (0)

// ---------------------------------------------------------------------------
// Compile-time Human3.6M skeleton tables (validated end-to-end r6-r12).
// ---------------------------------------------------------------------------
struct CI { int col, dk, n, jl[3], kk[3]; };
constexpr CI TAB0[9] = {          // half 0: out joints 0..7, cols 0..8
  {0,  0, 3, {1,4,7}, {4,12,20}},
  {1,  5, 2, {0,2,0}, {1,7,0}},
  {2,  8, 2, {1,3,0}, {6,10,0}},
  {3, 11, 1, {2,0,0}, {9,0,0}},
  {4, 13, 2, {0,5,0}, {2,15,0}},
  {5, 16, 2, {4,6,0}, {14,18,0}},
  {6, 19, 1, {5,0,0}, {17,0,0}},
  {7, 21, 1, {0,0,0}, {3,0,0}},
  {8, -1, 1, {7,0,0}, {22,0,0}},
};
constexpr CI TAB1[10] = {         // half 1: out joints 8..16 (local j-8), cols 7..16
  {7, -1, 1, {0,0,0}, {23,0,0}},
  {8, 24, 3, {1,3,6}, {28,33,41}},
  {9, 29, 2, {0,2,0}, {25,31,0}},
  {10,32, 1, {1,0,0}, {30,0,0}},
  {11,34, 2, {0,4,0}, {26,36,0}},
  {12,37, 2, {3,5,0}, {35,39,0}},
  {13,40, 1, {4,0,0}, {38,0,0}},
  {14,42, 2, {0,7,0}, {27,44,0}},
  {15,45, 2, {6,8,0}, {43,47,0}},
  {16,48, 1, {7,0,0}, {46,0,0}},
};
constexpr int RP[NJ + 1] = {0,4,7,10,12,15,18,20,23,28,31,33,36,39,41,44,47,49};

// Early-flush schedule (validated r12): local out-joints done after each col.
constexpr int FL0[9][2]  = {{-1,-1},{-1,-1},{1,-1},{2,3},{-1,-1},
                            {4,-1},{5,6},{0,-1},{7,-1}};
constexpr int FL1[10][2] = {{-1,-1},{-1,-1},{-1,-1},{1,2},{-1,-1},
                            {3,-1},{4,5},{0,-1},{6,-1},{7,8}};

// ---------------------------------------------------------------------------
// Prep (17 blocks x 256) — unchanged (validated r6-r12).
// ---------------------------------------------------------------------------
__global__ void prep_pack_kernel(const float* __restrict__ W,
                                 const float* __restrict__ e,
                                 bf16x8* __restrict__ Wpack,
                                 ushort* __restrict__ wt) {
  const int tid = threadIdx.x;
  if (blockIdx.x < 16) {
    const int idx = blockIdx.x * 256 + tid, n = idx >> 4, kb = idx & 15;
    const float* Wp = W + (size_t)(n >> 7) * (FD * NC) + (n & 127);
    bf16x8 v;
#pragma unroll
    for (int q = 0; q < 8; ++q) v[q] = (short)f2bf(Wp[(size_t)(kb * 8 + q) * NC]);
    Wpack[idx] = v;
  } else if (tid < NC) {
    const int c = tid;
    for (int j = 0; j < NJ; ++j) {
      const int k0 = RP[j], k1 = RP[j + 1];
      float m = -1e30f;
      for (int k = k0; k < k1; ++k) m = fmaxf(m, e[c * NNZ + k]);
      float s = 0.f;
      for (int k = k0; k < k1; ++k) s += expf(e[c * NNZ + k] - m);
      const float inv = 1.f / s;
      for (int k = k0; k < k1; ++k) wt[c * 64 + k] = f2bf(expf(e[c * NNZ + k] - m) * inv);
    }
    for (int k = NNZ; k < 64; ++k) wt[c * 64 + k] = 0;
  }
}

// ---------------------------------------------------------------------------
// Block = (tile-group of TPB, half), 512 thr = 8 waves x 16 channels = all 128.
// LDS double-buffer; next tile staged in 5 pair-chunks interleaved with the
// current tile's columns (chunk k: load @ col k, ds_write @ col k+2) so only
// 2 chunks (16 VGPR) are ever live. Early-flush stores (r12) keep acc <= 6.
// One lgkm-only barrier per tile.
// ---------------------------------------------------------------------------
template <int HALF>
__device__ __forceinline__ void run(const float* __restrict__ x,
                                    const bf16x8* __restrict__ Wpack,
                                    const ushort* __restrict__ wt,
                                    float* __restrict__ out,
                                    char* b0, char* b1, int group, int tid) {
  constexpr int COL0 = HALF ? 7 : 0;
  constexpr int NCOL = HALF ? 10 : 9;
  constexpr int JN   = HALF ? 9 : 8;
  constexpr int JB   = HALF ? 8 : 0;
  constexpr int NW   = HALF ? 5 : 3;
  constexpr int WB   = HALF ? 2 : 0;
  constexpr int NGRP = FPT * NCOL * 16;   // 8-float groups (half0 2304, half1 2560)
  const CI* TT = HALF ? TAB1 : TAB0;
  const int (*FL)[2] = HALF ? FL1 : FL0;

  const int w = tid >> 6, lane = tid & 63, l15 = lane & 15, l4 = lane >> 4;
  const int c = w * 16 + l15;

  // persistent B frags (32) + softmax-weight rows (12/20)
  bf16x8 bfr[2][4];
#pragma unroll
  for (int sel = 0; sel < 2; ++sel)
#pragma unroll
    for (int ks = 0; ks < 4; ++ks)
      bfr[sel][ks] = Wpack[(sel * 128 + c) * 16 + ks * 4 + l4];
  bf16x8 wtp[NW];
#pragma unroll
  for (int r = 0; r < NW; ++r)
    wtp[r] = *(const bf16x8*)(wt + c * 64 + (WB + r) * 8);

  float4 v[2][2];   // 2 chunk slots x float4-pair; chunk k -> slot k&1

#define LOADC(T, K) do {                                                  \
    int g_ = tid + (K) * 512;                                             \
    if ((K) >= 4 && g_ > NGRP - 1) g_ = NGRP - 1;                         \
    const int fr_ = g_ / (NCOL * 16), rem_ = g_ - fr_ * (NCOL * 16);      \
    const float* sp_ = x + ((size_t)(T) * FPT + fr_) * XROW +             \
                       COL0 * FD + rem_ * 8;                              \
    v[(K) & 1][0] = *(const float4*)sp_;                                  \
    v[(K) & 1][1] = *(const float4*)(sp_ + 4);                            \
  } while (0)

#define STWC(K, BUF) do {                                                 \
    const int g_ = tid + (K) * 512;                                       \
    if ((K) < 4 || g_ < NGRP) {                                           \
      const int fr_ = g_ / (NCOL * 16);                                   \
      const int byte_ = (g_ * 16) ^ ((fr_ & 7) << 4);                     \
      *(bf16x8*)((BUF) + byte_) = pack8(v[(K) & 1][0], v[(K) & 1][1]);    \
    }                                                                     \
  } while (0)

  const int t0 = group * TPB;

  // prologue: stage tile 0 into b0 (shallow pipeline, <=2 chunks live)
  LOADC(t0, 0); LOADC(t0, 1);
  STWC(0, b0); LOADC(t0, 2);
  STWC(1, b0); LOADC(t0, 3);
  STWC(2, b0); LOADC(t0, 4);
  STWC(3, b0); STWC(4, b0);
  BARR();

  f32x4 oa[JN];
#pragma unroll
  for (int j = 0; j < JN; ++j) oa[j] = (f32x4){0.f, 0.f, 0.f, 0.f};

#pragma unroll
  for (int i = 0; i < TPB; ++i) {
    const char* cur = (i & 1) ? b1 : b0;
    char* nxt = (i & 1) ? b0 : b1;
    const int t = t0 + i;
    const bool more = (i + 1 < TPB);
    float* const ob = out + (size_t)t * (FPT * XROW);

#pragma unroll
    for (int ci = 0; ci < NCOL; ++ci) {
      // ---- interleaved staging of tile i+1 (chunk ci-2 write, chunk ci load)
      if (more) {
        if (ci >= 2 && ci - 2 < 5) STWC(ci - 2, nxt);
        if (ci < 5) LOADC(t + 1, ci);
      }
      // ---- compute col ci from cur (r7/r12-verbatim, validated) ----
      const int dk = TT[ci].dk, nn = TT[ci].n;
      bf16x8 af[4];
#pragma unroll
      for (int ks = 0; ks < 4; ++ks) {
        const int byte = l15 * (NCOL * 256) + ci * 256 +
                         (((ks * 4 + l4) * 16) ^ ((l15 & 7) << 4));
        af[ks] = *(const bf16x8*)(cur + byte);
      }
      f32x4 h1 = (f32x4){0.f, 0.f, 0.f, 0.f};
#pragma unroll
      for (int ks = 0; ks < 4; ++ks)
        h1 = __builtin_amdgcn_mfma_f32_16x16x32_bf16(af[ks], bfr[1][ks], h1, 0, 0, 0);
      if (dk >= 0) {                       // diagonal term (W0 product)
        f32x4 h0 = (f32x4){0.f, 0.f, 0.f, 0.f};
#pragma unroll
        for (int ks = 0; ks < 4; ++ks)
          h0 = __builtin_amdgcn_mfma_f32_16x16x32_bf16(af[ks], bfr[0][ks], h0, 0, 0, 0);
        axpy(oa[TT[ci].col - JB], bf2f((ushort)wtp[(dk >> 3) - WB][dk & 7]), h0);
      }
#pragma unroll
      for (int o = 0; o < 3; ++o)
        if (o < nn)
          axpy(oa[TT[ci].jl[o]],
               bf2f((ushort)wtp[(TT[ci].kk[o] >> 3) - WB][TT[ci].kk[o] & 7]), h1);

      // ---- early flush: store + reset completed joints ----
#pragma unroll
      for (int fi = 0; fi < 2; ++fi) {
        const int fj = FL[ci][fi];
        if (fj >= 0) {
#pragma unroll
          for (int q = 0; q < 4; ++q)
            ob[(size_t)(l4 * 4 + q) * XROW + (JB + fj) * FD + c] = oa[fj][q];
          oa[fj] = (f32x4){0.f, 0.f, 0.f, 0.f};
        }
      }
      __builtin_amdgcn_sched_barrier(0);   // pin per-col schedule (reg budget)
    }
    BARR();   // staged writes visible; all waves done reading cur
  }
#undef LOADC
#undef STWC
}

// ---------------------------------------------------------------------------
__global__ __launch_bounds__(512, 4) void fused_kernel(
    const float*  __restrict__ x,
    const bf16x8* __restrict__ Wpack,
    const ushort* __restrict__ wt,
    float*        __restrict__ out) {
  __shared__ __align__(16) char xs[2 * BUFB];   // 80 KB -> 2 blocks/CU
  const int group = blockIdx.x >> 1;
  if (blockIdx.x & 1)
    run<1>(x, Wpack, wt, out, xs, xs + BUFB, group, threadIdx.x);
  else
    run<0>(x, Wpack, wt, out, xs, xs + BUFB, group, threadIdx.x);
}

// ---------------------------------------------------------------------------
extern "C" void kernel_launch(void* const* d_in, const int* in_sizes, int n_in,
                              void* d_out, int out_size, void* d_ws, size_t ws_size,
                              hipStream_t stream) {
  const float* x = (const float*)d_in[0];   // [B,T,J,F]
  const float* W = (const float*)d_in[1];   // [2,F,C]
  const float* e = (const float*)d_in[2];   // [C,NNZ]
  float* out = (float*)d_out;

  bf16x8* Wpack = (bf16x8*)d_ws;
  ushort* wt    = (ushort*)((char*)d_ws + WS_WT);

  prep_pack_kernel<<<17, 256, 0, stream>>>(W, e, Wpack, wt);

  const int frames = in_sizes[0] / XROW;    // 15552
  const int ntiles = frames / FPT;          // 972
  const int blocks = (ntiles / TPB) * 2;    // 486
  fused_kernel<<<blocks, 512, 0, stream>>>(x, Wpack, wt, out);
}